// Round 1
// baseline (5770.551 us; speedup 1.0000x reference)
//
#include <hip/hip_runtime.h>

#define D 128
#define GEMM_ROWS 64

// ---------------- degree histogram ----------------
__global__ __launch_bounds__(256) void degree_kernel(
    const int* __restrict__ src, const int* __restrict__ dst,
    float* __restrict__ deg_src, float* __restrict__ deg_dst, int E)
{
    int e = blockIdx.x * blockDim.x + threadIdx.x;
    if (e >= E) return;
    atomicAdd(&deg_src[src[e]], 1.0f);
    atomicAdd(&deg_dst[dst[e]], 1.0f);
}

// ---------------- rsqrt(max(deg,1)) in place ----------------
__global__ __launch_bounds__(256) void norm_kernel(
    float* __restrict__ deg_src, float* __restrict__ deg_dst, int N)
{
    int i = blockIdx.x * blockDim.x + threadIdx.x;
    if (i >= N) return;
    deg_src[i] = rsqrtf(fmaxf(deg_src[i], 1.0f));
    deg_dst[i] = rsqrtf(fmaxf(deg_dst[i], 1.0f));
}

// ---------------- edge-parallel scatter-add SpMM ----------------
// 32 lanes per edge; each lane handles 4 consecutive features (float4).
__global__ __launch_bounds__(256) void scatter_kernel(
    const float* __restrict__ h, const int* __restrict__ src,
    const int* __restrict__ dst, const float* __restrict__ norm_src,
    float* __restrict__ agg, int E)
{
    long long tid = (long long)blockIdx.x * blockDim.x + threadIdx.x;
    int e    = (int)(tid >> 5);
    int lane = (int)(tid & 31);
    if (e >= E) return;
    int s = src[e];
    int d = dst[e];
    float ns = norm_src[s];
    float4 v = ((const float4*)h)[s * (D / 4) + lane];
    float* base = agg + (long long)d * D + lane * 4;
    atomicAdd(base + 0, v.x * ns);
    atomicAdd(base + 1, v.y * ns);
    atomicAdd(base + 2, v.z * ns);
    atomicAdd(base + 3, v.w * ns);
}

// ---------------- fused (A*norm_dst) @ W + b, relu ----------------
// Block: 256 threads, 64 rows. W staged in LDS in two 64-row halves.
// Thread (c = tid&31, r0 = tid>>5) computes rows r0+8i (i<8), cols 4c..4c+3.
__global__ __launch_bounds__(256) void gemm_relu_kernel(
    const float* __restrict__ A, const float* __restrict__ norm_dst,
    const float* __restrict__ W, const float* __restrict__ bias,
    float* __restrict__ out, int N)
{
    __shared__ float aT[GEMM_ROWS][D];  // 32 KB
    __shared__ float wT[64][D];         // 32 KB
    int tid  = threadIdx.x;
    int row0 = blockIdx.x * GEMM_ROWS;

    // load A tile (64 rows x 128), scaled by norm_dst
    #pragma unroll
    for (int i = 0; i < 8; ++i) {
        int q  = tid + 256 * i;   // float4 index within tile
        int r  = q >> 5;          // 32 float4 per row
        int c4 = q & 31;
        int n  = row0 + r;
        float4 v = make_float4(0.f, 0.f, 0.f, 0.f);
        if (n < N) {
            v = ((const float4*)A)[(long long)n * (D / 4) + c4];
            float nd = norm_dst[n];
            v.x *= nd; v.y *= nd; v.z *= nd; v.w *= nd;
        }
        *(float4*)&aT[r][c4 * 4] = v;
    }

    int c  = tid & 31;   // column group (4 cols)
    int r0 = tid >> 5;   // 0..7
    float4 bv = ((const float4*)bias)[c];
    float4 acc[8];
    #pragma unroll
    for (int i = 0; i < 8; ++i) acc[i] = make_float4(0.f, 0.f, 0.f, 0.f);

    for (int half = 0; half < 2; ++half) {
        __syncthreads();
        #pragma unroll
        for (int i = 0; i < 8; ++i) {
            int q  = tid + 256 * i;
            int kr = q >> 5;
            int c4 = q & 31;
            *(float4*)&wT[kr][c4 * 4] =
                ((const float4*)W)[(half * 64 + kr) * (D / 4) + c4];
        }
        __syncthreads();
        #pragma unroll 4
        for (int kk = 0; kk < 64; ++kk) {
            int k = half * 64 + kk;
            float4 w4 = *(const float4*)&wT[kk][c * 4];
            #pragma unroll
            for (int i = 0; i < 8; ++i) {
                float a = aT[r0 + 8 * i][k];
                acc[i].x = fmaf(a, w4.x, acc[i].x);
                acc[i].y = fmaf(a, w4.y, acc[i].y);
                acc[i].z = fmaf(a, w4.z, acc[i].z);
                acc[i].w = fmaf(a, w4.w, acc[i].w);
            }
        }
    }

    #pragma unroll
    for (int i = 0; i < 8; ++i) {
        int n = row0 + r0 + 8 * i;
        if (n < N) {
            float4 o;
            o.x = fmaxf(acc[i].x + bv.x, 0.f);
            o.y = fmaxf(acc[i].y + bv.y, 0.f);
            o.z = fmaxf(acc[i].z + bv.z, 0.f);
            o.w = fmaxf(acc[i].w + bv.w, 0.f);
            ((float4*)out)[(long long)n * (D / 4) + c] = o;
        }
    }
}

extern "C" void kernel_launch(void* const* d_in, const int* in_sizes, int n_in,
                              void* d_out, int out_size, void* d_ws, size_t ws_size,
                              hipStream_t stream)
{
    const float* features = (const float*)d_in[0];
    const int*   src      = (const int*)d_in[1];
    const int*   dst      = (const int*)d_in[2];
    const float* W1       = (const float*)d_in[3];
    const float* b1       = (const float*)d_in[4];
    const float* W2       = (const float*)d_in[5];
    const float* b2       = (const float*)d_in[6];
    float*       out      = (float*)d_out;

    const int N = in_sizes[0] / D;
    const int E = in_sizes[1];

    float* ws       = (float*)d_ws;
    float* norm_src = ws;                       // N floats
    float* norm_dst = ws + N;                   // N floats
    float* agg      = ws + 2 * (size_t)N;       // N*D floats
    float* h        = agg + (size_t)N * D;      // N*D floats

    // degrees -> norms
    hipMemsetAsync(norm_src, 0, 2 * (size_t)N * sizeof(float), stream);
    degree_kernel<<<(E + 255) / 256, 256, 0, stream>>>(src, dst, norm_src, norm_dst, E);
    norm_kernel<<<(N + 255) / 256, 256, 0, stream>>>(norm_src, norm_dst, N);

    const long long scatter_threads = (long long)E * 32;
    const int scatter_blocks = (int)((scatter_threads + 255) / 256);
    const int gemm_blocks = (N + GEMM_ROWS - 1) / GEMM_ROWS;

    // layer 1
    hipMemsetAsync(agg, 0, (size_t)N * D * sizeof(float), stream);
    scatter_kernel<<<scatter_blocks, 256, 0, stream>>>(features, src, dst, norm_src, agg, E);
    gemm_relu_kernel<<<gemm_blocks, 256, 0, stream>>>(agg, norm_dst, W1, b1, h, N);

    // layer 2
    hipMemsetAsync(agg, 0, (size_t)N * D * sizeof(float), stream);
    scatter_kernel<<<scatter_blocks, 256, 0, stream>>>(h, src, dst, norm_src, agg, E);
    gemm_relu_kernel<<<gemm_blocks, 256, 0, stream>>>(agg, norm_dst, W2, b2, out, N);
}

// Round 2
// 910.002 us; speedup vs baseline: 6.3413x; 6.3413x over previous
//
#include <hip/hip_runtime.h>

#define D 128
#define GEMM_ROWS 64

// ---------------- int degree histogram (src + dst) ----------------
__global__ __launch_bounds__(256) void hist_kernel(
    const int* __restrict__ src, const int* __restrict__ dst,
    int* __restrict__ cnt_src, int* __restrict__ cnt_dst, int E)
{
    int e = blockIdx.x * blockDim.x + threadIdx.x;
    if (e >= E) return;
    atomicAdd(&cnt_src[src[e]], 1);
    atomicAdd(&cnt_dst[dst[e]], 1);
}

// ---------------- norms from int degrees ----------------
__global__ __launch_bounds__(256) void norm_kernel(
    const int* __restrict__ cnt_src, const int* __restrict__ cnt_dst,
    float* __restrict__ norm_src, float* __restrict__ norm_dst, int N)
{
    int i = blockIdx.x * blockDim.x + threadIdx.x;
    if (i >= N) return;
    norm_src[i] = rsqrtf((float)max(cnt_src[i], 1));
    norm_dst[i] = rsqrtf((float)max(cnt_dst[i], 1));
}

// ---------------- single-block exclusive scan of cnt_dst -> row_ptr, cursor --
__global__ __launch_bounds__(1024) void scan_kernel(
    const int* __restrict__ cnt, int* __restrict__ row_ptr,
    int* __restrict__ cursor, int N, int E)
{
    __shared__ int sums[1024];
    int t = threadIdx.x;
    int chunk = (N + 1023) >> 10;
    int lo = t * chunk;
    int hi = min(lo + chunk, N);
    int s = 0;
    for (int i = lo; i < hi; ++i) s += cnt[i];
    sums[t] = s;
    __syncthreads();
    // Hillis-Steele inclusive scan over 1024 partial sums
    for (int off = 1; off < 1024; off <<= 1) {
        int v = 0;
        if (t >= off) v = sums[t - off];
        __syncthreads();
        if (t >= off) sums[t] += v;
        __syncthreads();
    }
    int run = (t == 0) ? 0 : sums[t - 1];
    for (int i = lo; i < hi; ++i) {
        int c = cnt[i];          // read before potential alias-write
        row_ptr[i] = run;
        cursor[i]  = run;
        run += c;
    }
    if (t == 0) row_ptr[N] = E;
}

// ---------------- CSR placement: col[pos] = src, bucketed by dst -----------
__global__ __launch_bounds__(256) void place_kernel(
    const int* __restrict__ src, const int* __restrict__ dst,
    int* __restrict__ cursor, int* __restrict__ col, int E)
{
    int e = blockIdx.x * blockDim.x + threadIdx.x;
    if (e >= E) return;
    int pos = atomicAdd(&cursor[dst[e]], 1);
    col[pos] = src[e];
}

// ---------------- y = x * scale[row] (float4) ------------------------------
__global__ __launch_bounds__(256) void scale_kernel(
    const float* __restrict__ x, const float* __restrict__ scale,
    float* __restrict__ y, int total4)
{
    int i = blockIdx.x * blockDim.x + threadIdx.x;
    if (i >= total4) return;
    int n = i >> 5;              // D/4 = 32 float4 per row
    float s = scale[n];
    float4 v = ((const float4*)x)[i];
    v.x *= s; v.y *= s; v.z *= s; v.w *= s;
    ((float4*)y)[i] = v;
}

// ---------------- gather aggregation: one wave64 per dst node --------------
// agg[n] = norm_dst[n] * sum_{e in CSR[n]} hs[col[e]]
__global__ __launch_bounds__(256) void aggregate_kernel(
    const float* __restrict__ hs, const int* __restrict__ row_ptr,
    const int* __restrict__ col, const float* __restrict__ norm_dst,
    float* __restrict__ agg, int N)
{
    int n = blockIdx.x * 4 + (threadIdx.x >> 6);
    if (n >= N) return;
    int lane = threadIdx.x & 63;
    int beg = row_ptr[n], end = row_ptr[n + 1];
    const float2* h2 = (const float2*)hs;
    float2 acc = make_float2(0.f, 0.f);
    int i = beg;
    for (; i + 4 <= end; i += 4) {
        int s0 = col[i], s1 = col[i + 1], s2 = col[i + 2], s3 = col[i + 3];
        float2 v0 = h2[s0 * 64 + lane];
        float2 v1 = h2[s1 * 64 + lane];
        float2 v2 = h2[s2 * 64 + lane];
        float2 v3 = h2[s3 * 64 + lane];
        acc.x += (v0.x + v1.x) + (v2.x + v3.x);
        acc.y += (v0.y + v1.y) + (v2.y + v3.y);
    }
    for (; i < end; ++i) {
        float2 v = h2[col[i] * 64 + lane];
        acc.x += v.x; acc.y += v.y;
    }
    float nd = norm_dst[n];
    ((float2*)agg)[n * 64 + lane] = make_float2(acc.x * nd, acc.y * nd);
}

// ---------------- fused A @ W + b, relu, optional row-scale ----------------
// Block: 256 threads, 64 rows. W staged in LDS in two 64-row halves.
__global__ __launch_bounds__(256) void gemm_relu_kernel(
    const float* __restrict__ A, const float* __restrict__ W,
    const float* __restrict__ bias, float* __restrict__ out,
    int N, const float* __restrict__ out_scale)
{
    __shared__ float aT[GEMM_ROWS][D];  // 32 KB
    __shared__ float wT[64][D];         // 32 KB
    int tid  = threadIdx.x;
    int row0 = blockIdx.x * GEMM_ROWS;

    #pragma unroll
    for (int i = 0; i < 8; ++i) {
        int q  = tid + 256 * i;
        int r  = q >> 5;
        int c4 = q & 31;
        int n  = row0 + r;
        float4 v = make_float4(0.f, 0.f, 0.f, 0.f);
        if (n < N) v = ((const float4*)A)[(long long)n * (D / 4) + c4];
        *(float4*)&aT[r][c4 * 4] = v;
    }

    int c  = tid & 31;
    int r0 = tid >> 5;
    float4 bv = ((const float4*)bias)[c];
    float4 acc[8];
    #pragma unroll
    for (int i = 0; i < 8; ++i) acc[i] = make_float4(0.f, 0.f, 0.f, 0.f);

    for (int half = 0; half < 2; ++half) {
        __syncthreads();
        #pragma unroll
        for (int i = 0; i < 8; ++i) {
            int q  = tid + 256 * i;
            int kr = q >> 5;
            int c4 = q & 31;
            *(float4*)&wT[kr][c4 * 4] =
                ((const float4*)W)[(half * 64 + kr) * (D / 4) + c4];
        }
        __syncthreads();
        #pragma unroll 4
        for (int kk = 0; kk < 64; ++kk) {
            float4 w4 = *(const float4*)&wT[kk][c * 4];
            int k = half * 64 + kk;
            #pragma unroll
            for (int i = 0; i < 8; ++i) {
                float a = aT[r0 + 8 * i][k];
                acc[i].x = fmaf(a, w4.x, acc[i].x);
                acc[i].y = fmaf(a, w4.y, acc[i].y);
                acc[i].z = fmaf(a, w4.z, acc[i].z);
                acc[i].w = fmaf(a, w4.w, acc[i].w);
            }
        }
    }

    #pragma unroll
    for (int i = 0; i < 8; ++i) {
        int n = row0 + r0 + 8 * i;
        if (n < N) {
            float s = out_scale ? out_scale[n] : 1.0f;
            float4 o;
            o.x = fmaxf(acc[i].x + bv.x, 0.f) * s;
            o.y = fmaxf(acc[i].y + bv.y, 0.f) * s;
            o.z = fmaxf(acc[i].z + bv.z, 0.f) * s;
            o.w = fmaxf(acc[i].w + bv.w, 0.f) * s;
            ((float4*)out)[(long long)n * (D / 4) + c] = o;
        }
    }
}

extern "C" void kernel_launch(void* const* d_in, const int* in_sizes, int n_in,
                              void* d_out, int out_size, void* d_ws, size_t ws_size,
                              hipStream_t stream)
{
    const float* features = (const float*)d_in[0];
    const int*   src      = (const int*)d_in[1];
    const int*   dst      = (const int*)d_in[2];
    const float* W1       = (const float*)d_in[3];
    const float* b1       = (const float*)d_in[4];
    const float* W2       = (const float*)d_in[5];
    const float* b2       = (const float*)d_in[6];
    float*       out      = (float*)d_out;

    const int N = in_sizes[0] / D;
    const int E = in_sizes[1];

    // workspace layout
    float* fws      = (float*)d_ws;
    float* hs       = fws;                         // N*D (scaled input / hidden)
    float* agg      = hs + (size_t)N * D;          // N*D
    float* norm_src = agg + (size_t)N * D;         // N
    float* norm_dst = norm_src + N;                // N
    int*   iws      = (int*)(norm_dst + N);
    int*   cnt_src  = iws;                         // N (reused as cursor)
    int*   cnt_dst  = iws + N;                     // N
    int*   row_ptr  = iws + 2 * (size_t)N;         // N+1
    int*   col      = row_ptr + N + 1;             // E
    int*   cursor   = cnt_src;                     // alias (cnt_src dead after norm)

    const int eb = (E + 255) / 256;
    const int nb = (N + 255) / 256;
    const int gemm_blocks = (N + GEMM_ROWS - 1) / GEMM_ROWS;

    // CSR build + norms
    hipMemsetAsync(iws, 0, 2 * (size_t)N * sizeof(int), stream);
    hist_kernel<<<eb, 256, 0, stream>>>(src, dst, cnt_src, cnt_dst, E);
    norm_kernel<<<nb, 256, 0, stream>>>(cnt_src, cnt_dst, norm_src, norm_dst, N);
    scan_kernel<<<1, 1024, 0, stream>>>(cnt_dst, row_ptr, cursor, N, E);
    place_kernel<<<eb, 256, 0, stream>>>(src, dst, cursor, col, E);

    // layer 1: hs = features * norm_src; agg = norm_dst * (A^ hs); h = relu(agg@W1+b1)*norm_src
    scale_kernel<<<(N * 32 + 255) / 256, 256, 0, stream>>>(features, norm_src, hs, N * 32);
    aggregate_kernel<<<(N + 3) / 4, 256, 0, stream>>>(hs, row_ptr, col, norm_dst, agg, N);
    gemm_relu_kernel<<<gemm_blocks, 256, 0, stream>>>(agg, W1, b1, hs, N, norm_src);

    // layer 2: agg = norm_dst * (A^ hs); out = relu(agg@W2+b2)
    aggregate_kernel<<<(N + 3) / 4, 256, 0, stream>>>(hs, row_ptr, col, norm_dst, agg, N);
    gemm_relu_kernel<<<gemm_blocks, 256, 0, stream>>>(agg, W2, b2, out, N, (const float*)nullptr);
}

// Round 3
// 691.178 us; speedup vs baseline: 8.3489x; 1.3166x over previous
//
#include <hip/hip_runtime.h>

#define D 128
#define GEMM_ROWS 64
#define SCAN_BLOCKS 256
#define SCAN_THREADS 256

// ---------------- int degree histogram (src + dst) ----------------
__global__ __launch_bounds__(256) void hist_kernel(
    const int* __restrict__ src, const int* __restrict__ dst,
    int* __restrict__ cnt_src, int* __restrict__ cnt_dst, int E)
{
    int e = blockIdx.x * blockDim.x + threadIdx.x;
    if (e >= E) return;
    atomicAdd(&cnt_src[src[e]], 1);
    atomicAdd(&cnt_dst[dst[e]], 1);
}

// ---------------- norms from int degrees ----------------
__global__ __launch_bounds__(256) void norm_kernel(
    const int* __restrict__ cnt_src, const int* __restrict__ cnt_dst,
    float* __restrict__ norm_src, float* __restrict__ norm_dst, int N)
{
    int i = blockIdx.x * blockDim.x + threadIdx.x;
    if (i >= N) return;
    norm_src[i] = rsqrtf((float)max(cnt_src[i], 1));
    norm_dst[i] = rsqrtf((float)max(cnt_dst[i], 1));
}

// ---------------- multi-block exclusive scan: pass 1 (block sums) ----------
__global__ __launch_bounds__(SCAN_THREADS) void scan_pass1(
    const int* __restrict__ cnt, int* __restrict__ blk_sums, int N)
{
    __shared__ int sh[SCAN_THREADS];
    int t = threadIdx.x, b = blockIdx.x;
    int g = b * SCAN_THREADS + t;
    const int total_threads = SCAN_BLOCKS * SCAN_THREADS;
    int chunk = (N + total_threads - 1) / total_threads;
    int lo = g * chunk, hi = min(lo + chunk, N);
    int s = 0;
    for (int i = lo; i < hi; ++i) s += cnt[i];
    sh[t] = s;
    __syncthreads();
    for (int off = SCAN_THREADS / 2; off > 0; off >>= 1) {
        if (t < off) sh[t] += sh[t + off];
        __syncthreads();
    }
    if (t == 0) blk_sums[b] = sh[0];
}

// ---------------- pass 2: exclusive scan of 256 block sums, in place -------
__global__ __launch_bounds__(SCAN_BLOCKS) void scan_pass2(int* __restrict__ blk_sums)
{
    __shared__ int sh[SCAN_BLOCKS];
    int t = threadIdx.x;
    sh[t] = blk_sums[t];
    __syncthreads();
    for (int off = 1; off < SCAN_BLOCKS; off <<= 1) {
        int v = 0;
        if (t >= off) v = sh[t - off];
        __syncthreads();
        if (t >= off) sh[t] += v;
        __syncthreads();
    }
    blk_sums[t] = (t == 0) ? 0 : sh[t - 1];
}

// ---------------- pass 3: recompute + write row_ptr / cursor ---------------
__global__ __launch_bounds__(SCAN_THREADS) void scan_pass3(
    const int* __restrict__ cnt, const int* __restrict__ blk_sums,
    int* __restrict__ row_ptr, int* __restrict__ cursor, int N, int E)
{
    __shared__ int sh[SCAN_THREADS];
    int t = threadIdx.x, b = blockIdx.x;
    int g = b * SCAN_THREADS + t;
    const int total_threads = SCAN_BLOCKS * SCAN_THREADS;
    int chunk = (N + total_threads - 1) / total_threads;
    int lo = g * chunk, hi = min(lo + chunk, N);
    int s = 0;
    for (int i = lo; i < hi; ++i) s += cnt[i];
    sh[t] = s;
    __syncthreads();
    for (int off = 1; off < SCAN_THREADS; off <<= 1) {
        int v = 0;
        if (t >= off) v = sh[t - off];
        __syncthreads();
        if (t >= off) sh[t] += v;
        __syncthreads();
    }
    int run = blk_sums[b] + ((t == 0) ? 0 : sh[t - 1]);
    for (int i = lo; i < hi; ++i) {
        int c = cnt[i];
        row_ptr[i] = run;
        cursor[i]  = run;
        run += c;
    }
    if (b == 0 && t == 0) row_ptr[N] = E;
}

// ---------------- CSR placement: col[pos] = src, bucketed by dst -----------
__global__ __launch_bounds__(256) void place_kernel(
    const int* __restrict__ src, const int* __restrict__ dst,
    int* __restrict__ cursor, int* __restrict__ col, int E)
{
    int e = blockIdx.x * blockDim.x + threadIdx.x;
    if (e >= E) return;
    int pos = atomicAdd(&cursor[dst[e]], 1);
    col[pos] = src[e];
}

// ---------------- gather aggregation: one wave64 per dst node --------------
// agg[n] = norm_dst[n] * sum_{e in CSR[n]} norm_src[col[e]] * hs[col[e]]
__global__ __launch_bounds__(256) void aggregate_kernel(
    const float* __restrict__ hs, const int* __restrict__ row_ptr,
    const int* __restrict__ col, const float* __restrict__ norm_src,
    const float* __restrict__ norm_dst, float* __restrict__ agg, int N)
{
    int n = blockIdx.x * 4 + (threadIdx.x >> 6);
    if (n >= N) return;
    int lane = threadIdx.x & 63;
    int beg = row_ptr[n], end = row_ptr[n + 1];
    const float2* h2 = (const float2*)hs;
    float2 acc = make_float2(0.f, 0.f);
    int i = beg;
    for (; i + 4 <= end; i += 4) {
        int s0 = col[i], s1 = col[i + 1], s2 = col[i + 2], s3 = col[i + 3];
        float n0 = norm_src[s0], n1 = norm_src[s1];
        float n2 = norm_src[s2], n3 = norm_src[s3];
        float2 v0 = h2[s0 * 64 + lane];
        float2 v1 = h2[s1 * 64 + lane];
        float2 v2 = h2[s2 * 64 + lane];
        float2 v3 = h2[s3 * 64 + lane];
        acc.x = fmaf(v0.x, n0, acc.x); acc.y = fmaf(v0.y, n0, acc.y);
        acc.x = fmaf(v1.x, n1, acc.x); acc.y = fmaf(v1.y, n1, acc.y);
        acc.x = fmaf(v2.x, n2, acc.x); acc.y = fmaf(v2.y, n2, acc.y);
        acc.x = fmaf(v3.x, n3, acc.x); acc.y = fmaf(v3.y, n3, acc.y);
    }
    for (; i < end; ++i) {
        int s = col[i];
        float ns = norm_src[s];
        float2 v = h2[s * 64 + lane];
        acc.x = fmaf(v.x, ns, acc.x); acc.y = fmaf(v.y, ns, acc.y);
    }
    float nd = norm_dst[n];
    ((float2*)agg)[n * 64 + lane] = make_float2(acc.x * nd, acc.y * nd);
}

// ---------------- fused A @ W + b, relu ------------------------------------
// Block: 256 threads, 64 rows. W staged in LDS in two 64-row halves.
__global__ __launch_bounds__(256) void gemm_relu_kernel(
    const float* __restrict__ A, const float* __restrict__ W,
    const float* __restrict__ bias, float* __restrict__ out, int N)
{
    __shared__ float aT[GEMM_ROWS][D];  // 32 KB
    __shared__ float wT[64][D];         // 32 KB
    int tid  = threadIdx.x;
    int row0 = blockIdx.x * GEMM_ROWS;

    #pragma unroll
    for (int i = 0; i < 8; ++i) {
        int q  = tid + 256 * i;
        int r  = q >> 5;
        int c4 = q & 31;
        int n  = row0 + r;
        float4 v = make_float4(0.f, 0.f, 0.f, 0.f);
        if (n < N) v = ((const float4*)A)[(long long)n * (D / 4) + c4];
        *(float4*)&aT[r][c4 * 4] = v;
    }

    int c  = tid & 31;
    int r0 = tid >> 5;
    float4 bv = ((const float4*)bias)[c];
    float4 acc[8];
    #pragma unroll
    for (int i = 0; i < 8; ++i) acc[i] = make_float4(0.f, 0.f, 0.f, 0.f);

    for (int half = 0; half < 2; ++half) {
        __syncthreads();
        #pragma unroll
        for (int i = 0; i < 8; ++i) {
            int q  = tid + 256 * i;
            int kr = q >> 5;
            int c4 = q & 31;
            *(float4*)&wT[kr][c4 * 4] =
                ((const float4*)W)[(half * 64 + kr) * (D / 4) + c4];
        }
        __syncthreads();
        #pragma unroll 4
        for (int kk = 0; kk < 64; ++kk) {
            float4 w4 = *(const float4*)&wT[kk][c * 4];
            int k = half * 64 + kk;
            #pragma unroll
            for (int i = 0; i < 8; ++i) {
                float a = aT[r0 + 8 * i][k];
                acc[i].x = fmaf(a, w4.x, acc[i].x);
                acc[i].y = fmaf(a, w4.y, acc[i].y);
                acc[i].z = fmaf(a, w4.z, acc[i].z);
                acc[i].w = fmaf(a, w4.w, acc[i].w);
            }
        }
    }

    #pragma unroll
    for (int i = 0; i < 8; ++i) {
        int n = row0 + r0 + 8 * i;
        if (n < N) {
            float4 o;
            o.x = fmaxf(acc[i].x + bv.x, 0.f);
            o.y = fmaxf(acc[i].y + bv.y, 0.f);
            o.z = fmaxf(acc[i].z + bv.z, 0.f);
            o.w = fmaxf(acc[i].w + bv.w, 0.f);
            ((float4*)out)[(long long)n * (D / 4) + c] = o;
        }
    }
}

extern "C" void kernel_launch(void* const* d_in, const int* in_sizes, int n_in,
                              void* d_out, int out_size, void* d_ws, size_t ws_size,
                              hipStream_t stream)
{
    const float* features = (const float*)d_in[0];
    const int*   src      = (const int*)d_in[1];
    const int*   dst      = (const int*)d_in[2];
    const float* W1       = (const float*)d_in[3];
    const float* b1       = (const float*)d_in[4];
    const float* W2       = (const float*)d_in[5];
    const float* b2       = (const float*)d_in[6];
    float*       out      = (float*)d_out;

    const int N = in_sizes[0] / D;
    const int E = in_sizes[1];

    // workspace layout
    float* fws      = (float*)d_ws;
    float* hs       = fws;                         // N*D (hidden activations)
    float* agg      = hs + (size_t)N * D;          // N*D
    float* norm_src = agg + (size_t)N * D;         // N
    float* norm_dst = norm_src + N;                // N
    int*   iws      = (int*)(norm_dst + N);
    int*   cnt_src  = iws;                         // N (reused as cursor)
    int*   cnt_dst  = iws + N;                     // N
    int*   row_ptr  = iws + 2 * (size_t)N;         // N+1
    int*   col      = row_ptr + N + 1;             // E
    int*   blk_sums = col + E;                     // SCAN_BLOCKS
    int*   cursor   = cnt_src;                     // alias (cnt_src dead after norm)

    const int eb = (E + 255) / 256;
    const int nb = (N + 255) / 256;
    const int gemm_blocks = (N + GEMM_ROWS - 1) / GEMM_ROWS;
    const int agg_blocks  = (N + 3) / 4;

    // CSR build + norms
    hipMemsetAsync(iws, 0, 2 * (size_t)N * sizeof(int), stream);
    hist_kernel<<<eb, 256, 0, stream>>>(src, dst, cnt_src, cnt_dst, E);
    norm_kernel<<<nb, 256, 0, stream>>>(cnt_src, cnt_dst, norm_src, norm_dst, N);
    scan_pass1<<<SCAN_BLOCKS, SCAN_THREADS, 0, stream>>>(cnt_dst, blk_sums, N);
    scan_pass2<<<1, SCAN_BLOCKS, 0, stream>>>(blk_sums);
    scan_pass3<<<SCAN_BLOCKS, SCAN_THREADS, 0, stream>>>(cnt_dst, blk_sums, row_ptr, cursor, N, E);
    place_kernel<<<eb, 256, 0, stream>>>(src, dst, cursor, col, E);

    // layer 1: agg = norm_dst * sum(norm_src * features); hs = relu(agg@W1+b1)
    aggregate_kernel<<<agg_blocks, 256, 0, stream>>>(features, row_ptr, col, norm_src, norm_dst, agg, N);
    gemm_relu_kernel<<<gemm_blocks, 256, 0, stream>>>(agg, W1, b1, hs, N);

    // layer 2: agg = norm_dst * sum(norm_src * hs); out = relu(agg@W2+b2)
    aggregate_kernel<<<agg_blocks, 256, 0, stream>>>(hs, row_ptr, col, norm_src, norm_dst, agg, N);
    gemm_relu_kernel<<<gemm_blocks, 256, 0, stream>>>(agg, W2, b2, out, N);
}

// Round 4
// 563.794 us; speedup vs baseline: 10.2352x; 1.2259x over previous
//
#include <hip/hip_runtime.h>

#define D 128
#define GEMM_ROWS 64
#define BSHIFT 9
#define BSIZE 512        // nodes per bucket
#define MAXB 512         // max buckets supported (N <= 262144)
#define CHUNK 8192       // edges per block in bucketing kernels

// ------- pass over edges: src-degree atomics + coarse dst-bucket histogram -
__global__ __launch_bounds__(256) void hist_bucket_kernel(
    const int* __restrict__ src, const int* __restrict__ dst,
    int* __restrict__ cnt_src, int* __restrict__ bucket_cnt, int E)
{
    __shared__ int lcnt[MAXB];
    int t = threadIdx.x;
    for (int i = t; i < MAXB; i += 256) lcnt[i] = 0;
    __syncthreads();
    int base = blockIdx.x * CHUNK;
    int end  = min(base + CHUNK, E);
    for (int i = base + t; i < end; i += 256) {
        atomicAdd(&cnt_src[src[i]], 1);
        atomicAdd(&lcnt[dst[i] >> BSHIFT], 1);
    }
    __syncthreads();
    for (int b = t; b < MAXB; b += 256)
        if (lcnt[b]) atomicAdd(&bucket_cnt[b], lcnt[b]);
}

// ------- scan 196 bucket counts (single small block) -----------------------
__global__ __launch_bounds__(MAXB) void bucket_scan_kernel(
    const int* __restrict__ bucket_cnt, int* __restrict__ bucket_ptr,
    int* __restrict__ bucket_cursor, int* __restrict__ row_ptr,
    int NB, int N, int E)
{
    __shared__ int sh[MAXB];
    int t = threadIdx.x;
    sh[t] = (t < NB) ? bucket_cnt[t] : 0;
    __syncthreads();
    for (int off = 1; off < MAXB; off <<= 1) {
        int v = (t >= off) ? sh[t - off] : 0;
        __syncthreads();
        sh[t] += v;
        __syncthreads();
    }
    int excl = (t == 0) ? 0 : sh[t - 1];
    if (t < NB) { bucket_ptr[t] = excl; bucket_cursor[t] = excl; }
    if (t == 0) { bucket_ptr[NB] = E; row_ptr[N] = E; }
}

// ------- scatter (src,dst) pairs into bucket-ordered array -----------------
__global__ __launch_bounds__(256) void bucket_scatter_kernel(
    const int* __restrict__ src, const int* __restrict__ dst,
    int* __restrict__ bucket_cursor, int2* __restrict__ pairs, int E)
{
    __shared__ int lcnt[MAXB];
    __shared__ int lbase[MAXB];
    int t = threadIdx.x;
    for (int i = t; i < MAXB; i += 256) lcnt[i] = 0;
    __syncthreads();
    int base = blockIdx.x * CHUNK;
    int end  = min(base + CHUNK, E);
    for (int i = base + t; i < end; i += 256)
        atomicAdd(&lcnt[dst[i] >> BSHIFT], 1);
    __syncthreads();
    for (int b = t; b < MAXB; b += 256) {
        int c = lcnt[b];
        lbase[b] = c ? atomicAdd(&bucket_cursor[b], c) : 0;
        lcnt[b] = 0;
    }
    __syncthreads();
    for (int i = base + t; i < end; i += 256) {
        int d = dst[i];
        int b = d >> BSHIFT;
        int slot = lbase[b] + atomicAdd(&lcnt[b], 1);
        pairs[slot] = make_int2(src[i], d);
    }
}

// ------- per-bucket fine CSR: row_ptr, norm_dst, col -----------------------
__global__ __launch_bounds__(256) void fine_place_kernel(
    const int2* __restrict__ pairs, const int* __restrict__ bucket_ptr,
    int* __restrict__ row_ptr, float* __restrict__ norm_dst,
    int* __restrict__ col, int N)
{
    __shared__ int lcnt[BSIZE];
    __shared__ int lptr[BSIZE];
    int b = blockIdx.x, t = threadIdx.x;
    int nbase = b << BSHIFT;
    int beg = bucket_ptr[b], end = bucket_ptr[b + 1];
    lcnt[t] = 0; lcnt[t + 256] = 0;
    __syncthreads();
    for (int i = beg + t; i < end; i += 256)
        atomicAdd(&lcnt[pairs[i].y - nbase], 1);
    __syncthreads();
    // inclusive scan over 512 entries, 2 per thread
    for (int off = 1; off < BSIZE; off <<= 1) {
        int i0 = t, i1 = t + 256;
        int v0 = (i0 >= off) ? lcnt[i0 - off] : 0;
        int v1 = (i1 >= off) ? lcnt[i1 - off] : 0;
        __syncthreads();
        lcnt[i0] += v0; lcnt[i1] += v1;
        __syncthreads();
    }
    for (int j = t; j < BSIZE; j += 256) {
        int incl = lcnt[j];
        int excl = (j == 0) ? 0 : lcnt[j - 1];
        int node = nbase + j;
        if (node < N) {
            row_ptr[node] = beg + excl;
            norm_dst[node] = rsqrtf((float)max(incl - excl, 1));
        }
        lptr[j] = beg + excl;
    }
    __syncthreads();
    for (int i = beg + t; i < end; i += 256) {
        int2 p = pairs[i];
        int slot = atomicAdd(&lptr[p.y - nbase], 1);
        col[slot] = p.x;
    }
}

// ------- norm_src from src degrees -----------------------------------------
__global__ __launch_bounds__(256) void norm_src_kernel(
    const int* __restrict__ cnt_src, float* __restrict__ norm_src, int N)
{
    int i = blockIdx.x * blockDim.x + threadIdx.x;
    if (i >= N) return;
    norm_src[i] = rsqrtf((float)max(cnt_src[i], 1));
}

// ---------------- gather aggregation: one wave64 per dst node --------------
// agg[n] = norm_dst[n] * sum_{e in CSR[n]} norm_src[col[e]] * hs[col[e]]
__global__ __launch_bounds__(256) void aggregate_kernel(
    const float* __restrict__ hs, const int* __restrict__ row_ptr,
    const int* __restrict__ col, const float* __restrict__ norm_src,
    const float* __restrict__ norm_dst, float* __restrict__ agg, int N)
{
    int n = blockIdx.x * 4 + (threadIdx.x >> 6);
    if (n >= N) return;
    int lane = threadIdx.x & 63;
    int beg = row_ptr[n], end = row_ptr[n + 1];
    const float2* h2 = (const float2*)hs;
    float2 acc = make_float2(0.f, 0.f);
    int i = beg;
    for (; i + 4 <= end; i += 4) {
        int s0 = col[i], s1 = col[i + 1], s2 = col[i + 2], s3 = col[i + 3];
        float n0 = norm_src[s0], n1 = norm_src[s1];
        float n2 = norm_src[s2], n3 = norm_src[s3];
        float2 v0 = h2[s0 * 64 + lane];
        float2 v1 = h2[s1 * 64 + lane];
        float2 v2 = h2[s2 * 64 + lane];
        float2 v3 = h2[s3 * 64 + lane];
        acc.x = fmaf(v0.x, n0, acc.x); acc.y = fmaf(v0.y, n0, acc.y);
        acc.x = fmaf(v1.x, n1, acc.x); acc.y = fmaf(v1.y, n1, acc.y);
        acc.x = fmaf(v2.x, n2, acc.x); acc.y = fmaf(v2.y, n2, acc.y);
        acc.x = fmaf(v3.x, n3, acc.x); acc.y = fmaf(v3.y, n3, acc.y);
    }
    for (; i < end; ++i) {
        int s = col[i];
        float ns = norm_src[s];
        float2 v = h2[s * 64 + lane];
        acc.x = fmaf(v.x, ns, acc.x); acc.y = fmaf(v.y, ns, acc.y);
    }
    float nd = norm_dst[n];
    ((float2*)agg)[n * 64 + lane] = make_float2(acc.x * nd, acc.y * nd);
}

// ---------------- fused A @ W + b, relu ------------------------------------
__global__ __launch_bounds__(256) void gemm_relu_kernel(
    const float* __restrict__ A, const float* __restrict__ W,
    const float* __restrict__ bias, float* __restrict__ out, int N)
{
    __shared__ float aT[GEMM_ROWS][D];  // 32 KB
    __shared__ float wT[64][D];         // 32 KB
    int tid  = threadIdx.x;
    int row0 = blockIdx.x * GEMM_ROWS;

    #pragma unroll
    for (int i = 0; i < 8; ++i) {
        int q  = tid + 256 * i;
        int r  = q >> 5;
        int c4 = q & 31;
        int n  = row0 + r;
        float4 v = make_float4(0.f, 0.f, 0.f, 0.f);
        if (n < N) v = ((const float4*)A)[(long long)n * (D / 4) + c4];
        *(float4*)&aT[r][c4 * 4] = v;
    }

    int c  = tid & 31;
    int r0 = tid >> 5;
    float4 bv = ((const float4*)bias)[c];
    float4 acc[8];
    #pragma unroll
    for (int i = 0; i < 8; ++i) acc[i] = make_float4(0.f, 0.f, 0.f, 0.f);

    for (int half = 0; half < 2; ++half) {
        __syncthreads();
        #pragma unroll
        for (int i = 0; i < 8; ++i) {
            int q  = tid + 256 * i;
            int kr = q >> 5;
            int c4 = q & 31;
            *(float4*)&wT[kr][c4 * 4] =
                ((const float4*)W)[(half * 64 + kr) * (D / 4) + c4];
        }
        __syncthreads();
        #pragma unroll 4
        for (int kk = 0; kk < 64; ++kk) {
            float4 w4 = *(const float4*)&wT[kk][c * 4];
            int k = half * 64 + kk;
            #pragma unroll
            for (int i = 0; i < 8; ++i) {
                float a = aT[r0 + 8 * i][k];
                acc[i].x = fmaf(a, w4.x, acc[i].x);
                acc[i].y = fmaf(a, w4.y, acc[i].y);
                acc[i].z = fmaf(a, w4.z, acc[i].z);
                acc[i].w = fmaf(a, w4.w, acc[i].w);
            }
        }
    }

    #pragma unroll
    for (int i = 0; i < 8; ++i) {
        int n = row0 + r0 + 8 * i;
        if (n < N) {
            float4 o;
            o.x = fmaxf(acc[i].x + bv.x, 0.f);
            o.y = fmaxf(acc[i].y + bv.y, 0.f);
            o.z = fmaxf(acc[i].z + bv.z, 0.f);
            o.w = fmaxf(acc[i].w + bv.w, 0.f);
            ((float4*)out)[(long long)n * (D / 4) + c] = o;
        }
    }
}

extern "C" void kernel_launch(void* const* d_in, const int* in_sizes, int n_in,
                              void* d_out, int out_size, void* d_ws, size_t ws_size,
                              hipStream_t stream)
{
    const float* features = (const float*)d_in[0];
    const int*   src      = (const int*)d_in[1];
    const int*   dst      = (const int*)d_in[2];
    const float* W1       = (const float*)d_in[3];
    const float* b1       = (const float*)d_in[4];
    const float* W2       = (const float*)d_in[5];
    const float* b2       = (const float*)d_in[6];
    float*       out      = (float*)d_out;

    const int N = in_sizes[0] / D;
    const int E = in_sizes[1];
    const int NB = (N + BSIZE - 1) >> BSHIFT;   // coarse buckets (196 @ N=100k)

    // workspace layout
    float* fws      = (float*)d_ws;
    float* hs       = fws;                         // N*D floats
    float* agg      = hs + (size_t)N * D;          // N*D floats
    int2*  pairs    = (int2*)agg;                  // E int2 — overlaid, dead before agg written
    float* norm_src = agg + (size_t)N * D;         // N
    float* norm_dst = norm_src + N;                // N
    int*   iws          = (int*)(norm_dst + N);
    int*   cnt_src      = iws;                     // N
    int*   bucket_cnt   = cnt_src + N;             // MAXB   (memset together with cnt_src)
    int*   row_ptr      = bucket_cnt + MAXB;       // N+1
    int*   col          = row_ptr + N + 1;         // E
    int*   bucket_ptr   = col + E;                 // MAXB+1
    int*   bucket_cursor= bucket_ptr + MAXB + 1;   // MAXB

    const int nb = (N + 255) / 256;
    const int ebk = (E + CHUNK - 1) / CHUNK;
    const int gemm_blocks = (N + GEMM_ROWS - 1) / GEMM_ROWS;
    const int agg_blocks  = (N + 3) / 4;

    // ---- CSR build (bucketed, write-coalesced) ----
    hipMemsetAsync(cnt_src, 0, ((size_t)N + MAXB) * sizeof(int), stream);
    hist_bucket_kernel<<<ebk, 256, 0, stream>>>(src, dst, cnt_src, bucket_cnt, E);
    norm_src_kernel<<<nb, 256, 0, stream>>>(cnt_src, norm_src, N);
    bucket_scan_kernel<<<1, MAXB, 0, stream>>>(bucket_cnt, bucket_ptr, bucket_cursor, row_ptr, NB, N, E);
    bucket_scatter_kernel<<<ebk, 256, 0, stream>>>(src, dst, bucket_cursor, pairs, E);
    fine_place_kernel<<<NB, 256, 0, stream>>>(pairs, bucket_ptr, row_ptr, norm_dst, col, N);

    // ---- layer 1 ----
    aggregate_kernel<<<agg_blocks, 256, 0, stream>>>(features, row_ptr, col, norm_src, norm_dst, agg, N);
    gemm_relu_kernel<<<gemm_blocks, 256, 0, stream>>>(agg, W1, b1, hs, N);

    // ---- layer 2 ----
    aggregate_kernel<<<agg_blocks, 256, 0, stream>>>(hs, row_ptr, col, norm_src, norm_dst, agg, N);
    gemm_relu_kernel<<<gemm_blocks, 256, 0, stream>>>(agg, W2, b2, out, N);
}

// Round 5
// 465.745 us; speedup vs baseline: 12.3899x; 1.2105x over previous
//
#include <hip/hip_runtime.h>

#define D 128
#define GEMM_ROWS 64
#define BSHIFT 9
#define BSIZE 512        // nodes per bucket
#define MAXB 512         // max buckets supported (N <= 262144)
#define CHUNK 8192       // edges per block in bucketing kernels

typedef unsigned int uint;
typedef unsigned short u16;

// ---- bf16 helpers (RNE) ----
__device__ __forceinline__ u16 f2bf(float f) {
    union { float f; uint u; } c; c.f = f;
    uint u = c.u;
    u += 0x7FFFu + ((u >> 16) & 1u);
    return (u16)(u >> 16);
}
__device__ __forceinline__ float bflo(uint u) {
    union { uint u; float f; } c; c.u = u << 16; return c.f;
}
__device__ __forceinline__ float bfhi(uint u) {
    union { uint u; float f; } c; c.u = u & 0xFFFF0000u; return c.f;
}

// ------- pass over edges: src-degree atomics + coarse dst-bucket histogram -
__global__ __launch_bounds__(256) void hist_bucket_kernel(
    const int* __restrict__ src, const int* __restrict__ dst,
    int* __restrict__ cnt_src, int* __restrict__ bucket_cnt, int E)
{
    __shared__ int lcnt[MAXB];
    int t = threadIdx.x;
    for (int i = t; i < MAXB; i += 256) lcnt[i] = 0;
    __syncthreads();
    int base = blockIdx.x * CHUNK;
    int end  = min(base + CHUNK, E);
    for (int i = base + t; i < end; i += 256) {
        atomicAdd(&cnt_src[src[i]], 1);
        atomicAdd(&lcnt[dst[i] >> BSHIFT], 1);
    }
    __syncthreads();
    for (int b = t; b < MAXB; b += 256)
        if (lcnt[b]) atomicAdd(&bucket_cnt[b], lcnt[b]);
}

// ------- scan bucket counts (single small block) ---------------------------
__global__ __launch_bounds__(MAXB) void bucket_scan_kernel(
    const int* __restrict__ bucket_cnt, int* __restrict__ bucket_ptr,
    int* __restrict__ bucket_cursor, int* __restrict__ row_ptr,
    int NB, int N, int E)
{
    __shared__ int sh[MAXB];
    int t = threadIdx.x;
    sh[t] = (t < NB) ? bucket_cnt[t] : 0;
    __syncthreads();
    for (int off = 1; off < MAXB; off <<= 1) {
        int v = (t >= off) ? sh[t - off] : 0;
        __syncthreads();
        sh[t] += v;
        __syncthreads();
    }
    int excl = (t == 0) ? 0 : sh[t - 1];
    if (t < NB) { bucket_ptr[t] = excl; bucket_cursor[t] = excl; }
    if (t == 0) { bucket_ptr[NB] = E; row_ptr[N] = E; }
}

// ------- scatter (src,dst) pairs into bucket-ordered array -----------------
__global__ __launch_bounds__(256) void bucket_scatter_kernel(
    const int* __restrict__ src, const int* __restrict__ dst,
    int* __restrict__ bucket_cursor, int2* __restrict__ pairs, int E)
{
    __shared__ int lcnt[MAXB];
    __shared__ int lbase[MAXB];
    int t = threadIdx.x;
    for (int i = t; i < MAXB; i += 256) lcnt[i] = 0;
    __syncthreads();
    int base = blockIdx.x * CHUNK;
    int end  = min(base + CHUNK, E);
    for (int i = base + t; i < end; i += 256)
        atomicAdd(&lcnt[dst[i] >> BSHIFT], 1);
    __syncthreads();
    for (int b = t; b < MAXB; b += 256) {
        int c = lcnt[b];
        lbase[b] = c ? atomicAdd(&bucket_cursor[b], c) : 0;
        lcnt[b] = 0;
    }
    __syncthreads();
    for (int i = base + t; i < end; i += 256) {
        int d = dst[i];
        int b = d >> BSHIFT;
        int slot = lbase[b] + atomicAdd(&lcnt[b], 1);
        pairs[slot] = make_int2(src[i], d);
    }
}

// ------- per-bucket fine CSR: row_ptr, norm_dst, col -----------------------
__global__ __launch_bounds__(256) void fine_place_kernel(
    const int2* __restrict__ pairs, const int* __restrict__ bucket_ptr,
    int* __restrict__ row_ptr, float* __restrict__ norm_dst,
    int* __restrict__ col, int N)
{
    __shared__ int lcnt[BSIZE];
    __shared__ int lptr[BSIZE];
    int b = blockIdx.x, t = threadIdx.x;
    int nbase = b << BSHIFT;
    int beg = bucket_ptr[b], end = bucket_ptr[b + 1];
    lcnt[t] = 0; lcnt[t + 256] = 0;
    __syncthreads();
    for (int i = beg + t; i < end; i += 256)
        atomicAdd(&lcnt[pairs[i].y - nbase], 1);
    __syncthreads();
    for (int off = 1; off < BSIZE; off <<= 1) {
        int i0 = t, i1 = t + 256;
        int v0 = (i0 >= off) ? lcnt[i0 - off] : 0;
        int v1 = (i1 >= off) ? lcnt[i1 - off] : 0;
        __syncthreads();
        lcnt[i0] += v0; lcnt[i1] += v1;
        __syncthreads();
    }
    for (int j = t; j < BSIZE; j += 256) {
        int incl = lcnt[j];
        int excl = (j == 0) ? 0 : lcnt[j - 1];
        int node = nbase + j;
        if (node < N) {
            row_ptr[node] = beg + excl;
            norm_dst[node] = rsqrtf((float)max(incl - excl, 1));
        }
        lptr[j] = beg + excl;
    }
    __syncthreads();
    for (int i = beg + t; i < end; i += 256) {
        int2 p = pairs[i];
        int slot = atomicAdd(&lptr[p.y - nbase], 1);
        col[slot] = p.x;
    }
}

// ------- norm_src from src degrees -----------------------------------------
__global__ __launch_bounds__(256) void norm_src_kernel(
    const int* __restrict__ cnt_src, float* __restrict__ norm_src, int N)
{
    int i = blockIdx.x * blockDim.x + threadIdx.x;
    if (i >= N) return;
    norm_src[i] = rsqrtf((float)max(cnt_src[i], 1));
}

// ------- fp32 -> bf16 (RNE), float4 -> ushort4 -----------------------------
__global__ __launch_bounds__(256) void convert_bf16_kernel(
    const float* __restrict__ x, u16* __restrict__ y, int total4)
{
    int i = blockIdx.x * 256 + threadIdx.x;
    if (i >= total4) return;
    float4 v = ((const float4*)x)[i];
    ushort4 o;
    o.x = f2bf(v.x); o.y = f2bf(v.y); o.z = f2bf(v.z); o.w = f2bf(v.w);
    ((ushort4*)y)[i] = o;
}

// ---------------- gather aggregation (bf16 rows): one wave64 per dst node --
// 16 lanes per row (uint4 = 8 bf16 / lane), 4 edges in flight per wave-instr.
// agg[n] = norm_dst[n] * sum_e norm_src[col[e]] * bf16row[col[e]]
__global__ __launch_bounds__(256) void aggregate_kernel(
    const u16* __restrict__ hs, const int* __restrict__ row_ptr,
    const int* __restrict__ col, const float* __restrict__ norm_src,
    const float* __restrict__ norm_dst, float* __restrict__ agg, int N)
{
    int n = blockIdx.x * 4 + (threadIdx.x >> 6);
    if (n >= N) return;
    int lane = threadIdx.x & 63;
    int g    = lane >> 4;     // edge-group 0..3
    int l16  = lane & 15;     // position within row (8 bf16 elems)
    int beg = row_ptr[n], end = row_ptr[n + 1];
    const uint4* h4 = (const uint4*)hs;

    float acc[8];
    #pragma unroll
    for (int j = 0; j < 8; ++j) acc[j] = 0.f;

    int i = beg + g;
    for (; i + 4 < end; i += 8) {
        int s0 = col[i], s1 = col[i + 4];
        float ns0 = norm_src[s0], ns1 = norm_src[s1];
        uint4 v0 = h4[(size_t)s0 * 16 + l16];
        uint4 v1 = h4[(size_t)s1 * 16 + l16];
        acc[0] = fmaf(bflo(v0.x), ns0, acc[0]);
        acc[1] = fmaf(bfhi(v0.x), ns0, acc[1]);
        acc[2] = fmaf(bflo(v0.y), ns0, acc[2]);
        acc[3] = fmaf(bfhi(v0.y), ns0, acc[3]);
        acc[4] = fmaf(bflo(v0.z), ns0, acc[4]);
        acc[5] = fmaf(bfhi(v0.z), ns0, acc[5]);
        acc[6] = fmaf(bflo(v0.w), ns0, acc[6]);
        acc[7] = fmaf(bfhi(v0.w), ns0, acc[7]);
        acc[0] = fmaf(bflo(v1.x), ns1, acc[0]);
        acc[1] = fmaf(bfhi(v1.x), ns1, acc[1]);
        acc[2] = fmaf(bflo(v1.y), ns1, acc[2]);
        acc[3] = fmaf(bfhi(v1.y), ns1, acc[3]);
        acc[4] = fmaf(bflo(v1.z), ns1, acc[4]);
        acc[5] = fmaf(bfhi(v1.z), ns1, acc[5]);
        acc[6] = fmaf(bflo(v1.w), ns1, acc[6]);
        acc[7] = fmaf(bfhi(v1.w), ns1, acc[7]);
    }
    if (i < end) {
        int s = col[i];
        float ns = norm_src[s];
        uint4 v = h4[(size_t)s * 16 + l16];
        acc[0] = fmaf(bflo(v.x), ns, acc[0]);
        acc[1] = fmaf(bfhi(v.x), ns, acc[1]);
        acc[2] = fmaf(bflo(v.y), ns, acc[2]);
        acc[3] = fmaf(bfhi(v.y), ns, acc[3]);
        acc[4] = fmaf(bflo(v.z), ns, acc[4]);
        acc[5] = fmaf(bfhi(v.z), ns, acc[5]);
        acc[6] = fmaf(bflo(v.w), ns, acc[6]);
        acc[7] = fmaf(bfhi(v.w), ns, acc[7]);
    }

    // reduce across the 4 edge-groups
    #pragma unroll
    for (int j = 0; j < 8; ++j) {
        acc[j] += __shfl_xor(acc[j], 16, 64);
        acc[j] += __shfl_xor(acc[j], 32, 64);
    }

    if (g == 0) {
        float nd = norm_dst[n];
        float4* o = (float4*)(agg + (size_t)n * D + l16 * 8);
        o[0] = make_float4(acc[0] * nd, acc[1] * nd, acc[2] * nd, acc[3] * nd);
        o[1] = make_float4(acc[4] * nd, acc[5] * nd, acc[6] * nd, acc[7] * nd);
    }
}

// ---------------- fused A @ W + b, relu; epilogue fp32 or bf16 -------------
template <bool BF16_OUT>
__global__ __launch_bounds__(256) void gemm_relu_kernel(
    const float* __restrict__ A, const float* __restrict__ W,
    const float* __restrict__ bias, float* __restrict__ out_f,
    u16* __restrict__ out_b, int N)
{
    __shared__ float aT[GEMM_ROWS][D];  // 32 KB
    __shared__ float wT[64][D];         // 32 KB
    int tid  = threadIdx.x;
    int row0 = blockIdx.x * GEMM_ROWS;

    #pragma unroll
    for (int i = 0; i < 8; ++i) {
        int q  = tid + 256 * i;
        int r  = q >> 5;
        int c4 = q & 31;
        int n  = row0 + r;
        float4 v = make_float4(0.f, 0.f, 0.f, 0.f);
        if (n < N) v = ((const float4*)A)[(long long)n * (D / 4) + c4];
        *(float4*)&aT[r][c4 * 4] = v;
    }

    int c  = tid & 31;
    int r0 = tid >> 5;
    float4 bv = ((const float4*)bias)[c];
    float4 acc[8];
    #pragma unroll
    for (int i = 0; i < 8; ++i) acc[i] = make_float4(0.f, 0.f, 0.f, 0.f);

    for (int half = 0; half < 2; ++half) {
        __syncthreads();
        #pragma unroll
        for (int i = 0; i < 8; ++i) {
            int q  = tid + 256 * i;
            int kr = q >> 5;
            int c4 = q & 31;
            *(float4*)&wT[kr][c4 * 4] =
                ((const float4*)W)[(half * 64 + kr) * (D / 4) + c4];
        }
        __syncthreads();
        #pragma unroll 4
        for (int kk = 0; kk < 64; ++kk) {
            float4 w4 = *(const float4*)&wT[kk][c * 4];
            int k = half * 64 + kk;
            #pragma unroll
            for (int i = 0; i < 8; ++i) {
                float a = aT[r0 + 8 * i][k];
                acc[i].x = fmaf(a, w4.x, acc[i].x);
                acc[i].y = fmaf(a, w4.y, acc[i].y);
                acc[i].z = fmaf(a, w4.z, acc[i].z);
                acc[i].w = fmaf(a, w4.w, acc[i].w);
            }
        }
    }

    #pragma unroll
    for (int i = 0; i < 8; ++i) {
        int n = row0 + r0 + 8 * i;
        if (n < N) {
            float4 o;
            o.x = fmaxf(acc[i].x + bv.x, 0.f);
            o.y = fmaxf(acc[i].y + bv.y, 0.f);
            o.z = fmaxf(acc[i].z + bv.z, 0.f);
            o.w = fmaxf(acc[i].w + bv.w, 0.f);
            if (BF16_OUT) {
                ushort4 ob;
                ob.x = f2bf(o.x); ob.y = f2bf(o.y);
                ob.z = f2bf(o.z); ob.w = f2bf(o.w);
                ((ushort4*)out_b)[(long long)n * (D / 4) + c] = ob;
            } else {
                ((float4*)out_f)[(long long)n * (D / 4) + c] = o;
            }
        }
    }
}

extern "C" void kernel_launch(void* const* d_in, const int* in_sizes, int n_in,
                              void* d_out, int out_size, void* d_ws, size_t ws_size,
                              hipStream_t stream)
{
    const float* features = (const float*)d_in[0];
    const int*   src      = (const int*)d_in[1];
    const int*   dst      = (const int*)d_in[2];
    const float* W1       = (const float*)d_in[3];
    const float* b1       = (const float*)d_in[4];
    const float* W2       = (const float*)d_in[5];
    const float* b2       = (const float*)d_in[6];
    float*       out      = (float*)d_out;

    const int N = in_sizes[0] / D;
    const int E = in_sizes[1];
    const int NB = (N + BSIZE - 1) >> BSHIFT;

    // workspace layout
    float* agg      = (float*)d_ws;                 // N*D floats (pairs overlaid)
    int2*  pairs    = (int2*)agg;                   // E int2 — dead before agg written
    u16*   feat_bf  = (u16*)(agg + (size_t)N * D);  // N*D bf16
    u16*   hs_bf    = feat_bf + (size_t)N * D;      // N*D bf16
    float* norm_src = (float*)(hs_bf + (size_t)N * D);  // N
    float* norm_dst = norm_src + N;                 // N
    int*   iws          = (int*)(norm_dst + N);
    int*   cnt_src      = iws;                      // N
    int*   bucket_cnt   = cnt_src + N;              // MAXB (memset with cnt_src)
    int*   row_ptr      = bucket_cnt + MAXB;        // N+1
    int*   col          = row_ptr + N + 1;          // E
    int*   bucket_ptr   = col + E;                  // MAXB+1
    int*   bucket_cursor= bucket_ptr + MAXB + 1;    // MAXB

    const int nb = (N + 255) / 256;
    const int ebk = (E + CHUNK - 1) / CHUNK;
    const int gemm_blocks = (N + GEMM_ROWS - 1) / GEMM_ROWS;
    const int agg_blocks  = (N + 3) / 4;
    const int cv_blocks   = (N * 32 + 255) / 256;

    // ---- CSR build (bucketed, write-coalesced) + feature conversion ----
    hipMemsetAsync(cnt_src, 0, ((size_t)N + MAXB) * sizeof(int), stream);
    hist_bucket_kernel<<<ebk, 256, 0, stream>>>(src, dst, cnt_src, bucket_cnt, E);
    norm_src_kernel<<<nb, 256, 0, stream>>>(cnt_src, norm_src, N);
    bucket_scan_kernel<<<1, MAXB, 0, stream>>>(bucket_cnt, bucket_ptr, bucket_cursor, row_ptr, NB, N, E);
    bucket_scatter_kernel<<<ebk, 256, 0, stream>>>(src, dst, bucket_cursor, pairs, E);
    fine_place_kernel<<<NB, 256, 0, stream>>>(pairs, bucket_ptr, row_ptr, norm_dst, col, N);
    convert_bf16_kernel<<<cv_blocks, 256, 0, stream>>>(features, feat_bf, N * 32);

    // ---- layer 1 ----
    aggregate_kernel<<<agg_blocks, 256, 0, stream>>>(feat_bf, row_ptr, col, norm_src, norm_dst, agg, N);
    gemm_relu_kernel<true><<<gemm_blocks, 256, 0, stream>>>(agg, W1, b1, nullptr, hs_bf, N);

    // ---- layer 2 ----
    aggregate_kernel<<<agg_blocks, 256, 0, stream>>>(hs_bf, row_ptr, col, norm_src, norm_dst, agg, N);
    gemm_relu_kernel<false><<<gemm_blocks, 256, 0, stream>>>(agg, W2, b2, out, nullptr, N);
}

// Round 6
// 449.497 us; speedup vs baseline: 12.8378x; 1.0361x over previous
//
#include <hip/hip_runtime.h>

#define D 128
#define BSHIFT 9
#define BSIZE 512        // nodes per bucket
#define MAXB 512         // max buckets supported (N <= 262144)
#define CHUNK 2048       // edges per block in bucketing kernels

typedef unsigned int uint;
typedef unsigned short u16;
typedef __attribute__((ext_vector_type(8))) short short8;
typedef __attribute__((ext_vector_type(4))) float floatx4;

// ---- bf16 helpers (RNE) ----
__device__ __forceinline__ u16 f2bf(float f) {
    union { float f; uint u; } c; c.f = f;
    uint u = c.u;
    u += 0x7FFFu + ((u >> 16) & 1u);
    return (u16)(u >> 16);
}
__device__ __forceinline__ float bflo(uint u) {
    union { uint u; float f; } c; c.u = u << 16; return c.f;
}
__device__ __forceinline__ float bfhi(uint u) {
    union { uint u; float f; } c; c.u = u & 0xFFFF0000u; return c.f;
}

// ------- coarse dst-bucket histogram (streaming, LDS only) -----------------
__global__ __launch_bounds__(256) void hist_bucket_kernel(
    const int* __restrict__ dst, int* __restrict__ bucket_cnt, int E)
{
    __shared__ int lcnt[MAXB];
    int t = threadIdx.x;
    for (int i = t; i < MAXB; i += 256) lcnt[i] = 0;
    __syncthreads();
    int base = blockIdx.x * CHUNK;
    int end  = min(base + CHUNK, E);
    for (int i = base + t; i < end; i += 256)
        atomicAdd(&lcnt[dst[i] >> BSHIFT], 1);
    __syncthreads();
    for (int b = t; b < MAXB; b += 256)
        if (lcnt[b]) atomicAdd(&bucket_cnt[b], lcnt[b]);
}

// ------- scan bucket counts (single small block) ---------------------------
__global__ __launch_bounds__(MAXB) void bucket_scan_kernel(
    const int* __restrict__ bucket_cnt, int* __restrict__ bucket_ptr,
    int* __restrict__ bucket_cursor, int* __restrict__ row_ptr,
    int NB, int N, int E)
{
    __shared__ int sh[MAXB];
    int t = threadIdx.x;
    sh[t] = (t < NB) ? bucket_cnt[t] : 0;
    __syncthreads();
    for (int off = 1; off < MAXB; off <<= 1) {
        int v = (t >= off) ? sh[t - off] : 0;
        __syncthreads();
        sh[t] += v;
        __syncthreads();
    }
    int excl = (t == 0) ? 0 : sh[t - 1];
    if (t < NB) { bucket_ptr[t] = excl; bucket_cursor[t] = excl; }
    if (t == 0) { bucket_ptr[NB] = E; row_ptr[N] = E; }
}

// ------- scatter (src,dst) pairs into bucket order + src-degree atomics ----
__global__ __launch_bounds__(256) void bucket_scatter_kernel(
    const int* __restrict__ src, const int* __restrict__ dst,
    int* __restrict__ bucket_cursor, int2* __restrict__ pairs,
    int* __restrict__ cnt_src, int E)
{
    __shared__ int lcnt[MAXB];
    __shared__ int lbase[MAXB];
    int t = threadIdx.x;
    for (int i = t; i < MAXB; i += 256) lcnt[i] = 0;
    __syncthreads();
    int base = blockIdx.x * CHUNK;
    int end  = min(base + CHUNK, E);
    for (int i = base + t; i < end; i += 256)
        atomicAdd(&lcnt[dst[i] >> BSHIFT], 1);
    __syncthreads();
    for (int b = t; b < MAXB; b += 256) {
        int c = lcnt[b];
        lbase[b] = c ? atomicAdd(&bucket_cursor[b], c) : 0;
        lcnt[b] = 0;
    }
    __syncthreads();
    for (int i = base + t; i < end; i += 256) {
        int d = dst[i];
        int s = src[i];
        atomicAdd(&cnt_src[s], 1);
        int b = d >> BSHIFT;
        int slot = lbase[b] + atomicAdd(&lcnt[b], 1);
        pairs[slot] = make_int2(s, d);
    }
}

// ------- per-bucket fine CSR: row_ptr, norm_dst, col -----------------------
__global__ __launch_bounds__(256) void fine_place_kernel(
    const int2* __restrict__ pairs, const int* __restrict__ bucket_ptr,
    int* __restrict__ row_ptr, float* __restrict__ norm_dst,
    int* __restrict__ col, int N)
{
    __shared__ int lcnt[BSIZE];
    __shared__ int lptr[BSIZE];
    int b = blockIdx.x, t = threadIdx.x;
    int nbase = b << BSHIFT;
    int beg = bucket_ptr[b], end = bucket_ptr[b + 1];
    lcnt[t] = 0; lcnt[t + 256] = 0;
    __syncthreads();
    for (int i = beg + t; i < end; i += 256)
        atomicAdd(&lcnt[pairs[i].y - nbase], 1);
    __syncthreads();
    for (int off = 1; off < BSIZE; off <<= 1) {
        int i0 = t, i1 = t + 256;
        int v0 = (i0 >= off) ? lcnt[i0 - off] : 0;
        int v1 = (i1 >= off) ? lcnt[i1 - off] : 0;
        __syncthreads();
        lcnt[i0] += v0; lcnt[i1] += v1;
        __syncthreads();
    }
    for (int j = t; j < BSIZE; j += 256) {
        int incl = lcnt[j];
        int excl = (j == 0) ? 0 : lcnt[j - 1];
        int node = nbase + j;
        if (node < N) {
            row_ptr[node] = beg + excl;
            norm_dst[node] = rsqrtf((float)max(incl - excl, 1));
        }
        lptr[j] = beg + excl;
    }
    __syncthreads();
    for (int i = beg + t; i < end; i += 256) {
        int2 p = pairs[i];
        int slot = atomicAdd(&lptr[p.y - nbase], 1);
        col[slot] = p.x;
    }
}

// ------- norm_src from src degrees -----------------------------------------
__global__ __launch_bounds__(256) void norm_src_kernel(
    const int* __restrict__ cnt_src, float* __restrict__ norm_src, int N)
{
    int i = blockIdx.x * blockDim.x + threadIdx.x;
    if (i >= N) return;
    norm_src[i] = rsqrtf((float)max(cnt_src[i], 1));
}

// ------- fp32 -> bf16 (RNE), float4 -> ushort4 -----------------------------
__global__ __launch_bounds__(256) void convert_bf16_kernel(
    const float* __restrict__ x, u16* __restrict__ y, int total4)
{
    int i = blockIdx.x * 256 + threadIdx.x;
    if (i >= total4) return;
    float4 v = ((const float4*)x)[i];
    ushort4 o;
    o.x = f2bf(v.x); o.y = f2bf(v.y); o.z = f2bf(v.z); o.w = f2bf(v.w);
    ((ushort4*)y)[i] = o;
}

// ------- W [k][n] fp32 -> W_T [n][k] bf16 ----------------------------------
__global__ __launch_bounds__(256) void convert_wT_kernel(
    const float* __restrict__ W, u16* __restrict__ WT)
{
    int i = blockIdx.x * 256 + threadIdx.x;   // i = k*128 + n
    int k = i >> 7, n = i & 127;
    WT[n * 128 + k] = f2bf(W[i]);
}

// ---------------- gather aggregation (bf16 rows) -> bf16 agg ---------------
// one wave64 per dst node; 16 lanes/row (uint4 = 8 bf16), 4 edges in flight.
__global__ __launch_bounds__(256) void aggregate_kernel(
    const u16* __restrict__ hs, const int* __restrict__ row_ptr,
    const int* __restrict__ col, const float* __restrict__ norm_src,
    const float* __restrict__ norm_dst, u16* __restrict__ agg, int N)
{
    int n = blockIdx.x * 4 + (threadIdx.x >> 6);
    if (n >= N) return;
    int lane = threadIdx.x & 63;
    int g    = lane >> 4;     // edge-group 0..3
    int l16  = lane & 15;     // position within row (8 bf16 elems)
    int beg = row_ptr[n], end = row_ptr[n + 1];
    const uint4* h4 = (const uint4*)hs;

    float acc[8];
    #pragma unroll
    for (int j = 0; j < 8; ++j) acc[j] = 0.f;

    int i = beg + g;
    for (; i + 4 < end; i += 8) {
        int s0 = col[i], s1 = col[i + 4];
        float ns0 = norm_src[s0], ns1 = norm_src[s1];
        uint4 v0 = h4[(size_t)s0 * 16 + l16];
        uint4 v1 = h4[(size_t)s1 * 16 + l16];
        acc[0] = fmaf(bflo(v0.x), ns0, acc[0]);
        acc[1] = fmaf(bfhi(v0.x), ns0, acc[1]);
        acc[2] = fmaf(bflo(v0.y), ns0, acc[2]);
        acc[3] = fmaf(bfhi(v0.y), ns0, acc[3]);
        acc[4] = fmaf(bflo(v0.z), ns0, acc[4]);
        acc[5] = fmaf(bfhi(v0.z), ns0, acc[5]);
        acc[6] = fmaf(bflo(v0.w), ns0, acc[6]);
        acc[7] = fmaf(bfhi(v0.w), ns0, acc[7]);
        acc[0] = fmaf(bflo(v1.x), ns1, acc[0]);
        acc[1] = fmaf(bfhi(v1.x), ns1, acc[1]);
        acc[2] = fmaf(bflo(v1.y), ns1, acc[2]);
        acc[3] = fmaf(bfhi(v1.y), ns1, acc[3]);
        acc[4] = fmaf(bflo(v1.z), ns1, acc[4]);
        acc[5] = fmaf(bfhi(v1.z), ns1, acc[5]);
        acc[6] = fmaf(bflo(v1.w), ns1, acc[6]);
        acc[7] = fmaf(bfhi(v1.w), ns1, acc[7]);
    }
    if (i < end) {
        int s = col[i];
        float ns = norm_src[s];
        uint4 v = h4[(size_t)s * 16 + l16];
        acc[0] = fmaf(bflo(v.x), ns, acc[0]);
        acc[1] = fmaf(bfhi(v.x), ns, acc[1]);
        acc[2] = fmaf(bflo(v.y), ns, acc[2]);
        acc[3] = fmaf(bfhi(v.y), ns, acc[3]);
        acc[4] = fmaf(bflo(v.z), ns, acc[4]);
        acc[5] = fmaf(bfhi(v.z), ns, acc[5]);
        acc[6] = fmaf(bflo(v.w), ns, acc[6]);
        acc[7] = fmaf(bfhi(v.w), ns, acc[7]);
    }

    #pragma unroll
    for (int j = 0; j < 8; ++j) {
        acc[j] += __shfl_xor(acc[j], 16, 64);
        acc[j] += __shfl_xor(acc[j], 32, 64);
    }

    if (g == 0) {
        float nd = norm_dst[n];
        ushort4 lo, hi;
        lo.x = f2bf(acc[0] * nd); lo.y = f2bf(acc[1] * nd);
        lo.z = f2bf(acc[2] * nd); lo.w = f2bf(acc[3] * nd);
        hi.x = f2bf(acc[4] * nd); hi.y = f2bf(acc[5] * nd);
        hi.z = f2bf(acc[6] * nd); hi.w = f2bf(acc[7] * nd);
        ushort4* o = (ushort4*)(agg + (size_t)n * D + l16 * 8);
        o[0] = lo; o[1] = hi;
    }
}

// ---------------- MFMA GEMM: out = relu(A @ W + b) -------------------------
// A: N x 128 bf16 row-major. WT: 128(n) x 128(k) bf16. 16x16x32 MFMA.
// Block = 4 waves; wave handles 32 rows x 128 cols (two 16-row strips).
// A-frag: A[m=lane&15][k=quad*8+j]; B-frag: W[k=quad*8+j][n=lane&15] = WT[n][k..];
// C/D: col=lane&15, row=quad*4+reg.
template <bool BF16_OUT>
__global__ __launch_bounds__(256) void gemm_mfma_kernel(
    const u16* __restrict__ A, const u16* __restrict__ WT,
    const float* __restrict__ bias, float* __restrict__ out_f,
    u16* __restrict__ out_b, int N)
{
    int wave = threadIdx.x >> 6;
    int lane = threadIdx.x & 63;
    int m16  = lane & 15;
    int quad = lane >> 4;
    int row_base = blockIdx.x * 128 + wave * 32;

    int rA0 = min(row_base + m16, N - 1);
    int rA1 = min(row_base + 16 + m16, N - 1);
    const short8* Arow0 = (const short8*)(A + (size_t)rA0 * D);
    const short8* Arow1 = (const short8*)(A + (size_t)rA1 * D);

    floatx4 acc0[8], acc1[8];
    #pragma unroll
    for (int c = 0; c < 8; ++c) {
        acc0[c] = (floatx4){0.f, 0.f, 0.f, 0.f};
        acc1[c] = (floatx4){0.f, 0.f, 0.f, 0.f};
    }

    #pragma unroll
    for (int q = 0; q < 4; ++q) {
        short8 a0 = Arow0[q * 4 + quad];
        short8 a1 = Arow1[q * 4 + quad];
        #pragma unroll
        for (int c = 0; c < 8; ++c) {
            short8 b = *(const short8*)(WT + (size_t)(c * 16 + m16) * D + q * 32 + quad * 8);
            acc0[c] = __builtin_amdgcn_mfma_f32_16x16x32_bf16(a0, b, acc0[c], 0, 0, 0);
            acc1[c] = __builtin_amdgcn_mfma_f32_16x16x32_bf16(a1, b, acc1[c], 0, 0, 0);
        }
    }

    #pragma unroll
    for (int c = 0; c < 8; ++c) {
        int colc = c * 16 + m16;
        float bv = bias[colc];
        #pragma unroll
        for (int r = 0; r < 4; ++r) {
            int row0 = row_base + quad * 4 + r;
            int row1 = row0 + 16;
            float v0 = fmaxf(acc0[c][r] + bv, 0.f);
            float v1 = fmaxf(acc1[c][r] + bv, 0.f);
            if (BF16_OUT) {
                if (row0 < N) out_b[(size_t)row0 * D + colc] = f2bf(v0);
                if (row1 < N) out_b[(size_t)row1 * D + colc] = f2bf(v1);
            } else {
                if (row0 < N) out_f[(size_t)row0 * D + colc] = v0;
                if (row1 < N) out_f[(size_t)row1 * D + colc] = v1;
            }
        }
    }
}

extern "C" void kernel_launch(void* const* d_in, const int* in_sizes, int n_in,
                              void* d_out, int out_size, void* d_ws, size_t ws_size,
                              hipStream_t stream)
{
    const float* features = (const float*)d_in[0];
    const int*   src      = (const int*)d_in[1];
    const int*   dst      = (const int*)d_in[2];
    const float* W1       = (const float*)d_in[3];
    const float* b1       = (const float*)d_in[4];
    const float* W2       = (const float*)d_in[5];
    const float* b2       = (const float*)d_in[6];
    float*       out      = (float*)d_out;

    const int N = in_sizes[0] / D;
    const int E = in_sizes[1];
    const int NB = (N + BSIZE - 1) >> BSHIFT;

    // workspace layout
    u16*   agg_bf   = (u16*)d_ws;                   // N*D bf16 (pairs overlaid)
    int2*  pairs    = (int2*)agg_bf;                // E int2 (12.8MB <= 25.6MB)
    u16*   feat_bf  = agg_bf + (size_t)N * D;       // N*D bf16
    u16*   hs_bf    = feat_bf + (size_t)N * D;      // N*D bf16
    u16*   wT1      = hs_bf + (size_t)N * D;        // 16384 bf16
    u16*   wT2      = wT1 + D * D;                  // 16384 bf16
    float* norm_src = (float*)(wT2 + D * D);        // N
    float* norm_dst = norm_src + N;                 // N
    int*   iws          = (int*)(norm_dst + N);
    int*   cnt_src      = iws;                      // N
    int*   bucket_cnt   = cnt_src + N;              // MAXB (memset with cnt_src)
    int*   row_ptr      = bucket_cnt + MAXB;        // N+1
    int*   col          = row_ptr + N + 1;          // E
    int*   bucket_ptr   = col + E;                  // MAXB+1
    int*   bucket_cursor= bucket_ptr + MAXB + 1;    // MAXB

    const int nb  = (N + 255) / 256;
    const int ebk = (E + CHUNK - 1) / CHUNK;
    const int gemm_blocks = (N + 127) / 128;
    const int agg_blocks  = (N + 3) / 4;
    const int cv_blocks   = (N * 32 + 255) / 256;
    const int wt_blocks   = (D * D + 255) / 256;

    // ---- CSR build (bucketed, write-coalesced) + conversions ----
    hipMemsetAsync(cnt_src, 0, ((size_t)N + MAXB) * sizeof(int), stream);
    hist_bucket_kernel<<<ebk, 256, 0, stream>>>(dst, bucket_cnt, E);
    bucket_scan_kernel<<<1, MAXB, 0, stream>>>(bucket_cnt, bucket_ptr, bucket_cursor, row_ptr, NB, N, E);
    bucket_scatter_kernel<<<ebk, 256, 0, stream>>>(src, dst, bucket_cursor, pairs, cnt_src, E);
    norm_src_kernel<<<nb, 256, 0, stream>>>(cnt_src, norm_src, N);
    fine_place_kernel<<<NB, 256, 0, stream>>>(pairs, bucket_ptr, row_ptr, norm_dst, col, N);
    convert_bf16_kernel<<<cv_blocks, 256, 0, stream>>>(features, feat_bf, N * 32);
    convert_wT_kernel<<<wt_blocks, 256, 0, stream>>>(W1, wT1);
    convert_wT_kernel<<<wt_blocks, 256, 0, stream>>>(W2, wT2);

    // ---- layer 1 ----
    aggregate_kernel<<<agg_blocks, 256, 0, stream>>>(feat_bf, row_ptr, col, norm_src, norm_dst, agg_bf, N);
    gemm_mfma_kernel<true><<<gemm_blocks, 256, 0, stream>>>(agg_bf, wT1, b1, nullptr, hs_bf, N);

    // ---- layer 2 ----
    aggregate_kernel<<<agg_blocks, 256, 0, stream>>>(hs_bf, row_ptr, col, norm_src, norm_dst, agg_bf, N);
    gemm_mfma_kernel<false><<<gemm_blocks, 256, 0, stream>>>(agg_bf, wT2, b2, out, nullptr, N);
}

// Round 7
// 424.415 us; speedup vs baseline: 13.5965x; 1.0591x over previous
//
#include <hip/hip_runtime.h>

#define D 128
#define BSHIFT 10
#define BSIZE 1024       // nodes per bucket
#define NBMAX 128        // max buckets (N <= 131072)
#define CHUNK 4096       // edges per block in bucketing kernels
#define SRCBITS 17
#define SRCMASK 0x1FFFF

typedef unsigned int uint;
typedef unsigned short u16;
typedef __attribute__((ext_vector_type(8))) short short8;
typedef __attribute__((ext_vector_type(4))) float floatx4;

// ---- bf16 helpers (RNE) ----
__device__ __forceinline__ u16 f2bf(float f) {
    union { float f; uint u; } c; c.f = f;
    uint u = c.u;
    u += 0x7FFFu + ((u >> 16) & 1u);
    return (u16)(u >> 16);
}
__device__ __forceinline__ float bflo(uint u) {
    union { uint u; float f; } c; c.u = u << 16; return c.f;
}
__device__ __forceinline__ float bfhi(uint u) {
    union { uint u; float f; } c; c.u = u & 0xFFFF0000u; return c.f;
}

// ------- edges pass 1: src-degree atomics + coarse dst-bucket histogram ----
__global__ __launch_bounds__(256) void hist_bucket_kernel(
    const int* __restrict__ src, const int* __restrict__ dst,
    int* __restrict__ cnt_src, int* __restrict__ bucket_cnt, int E)
{
    __shared__ int lcnt[NBMAX];
    int t = threadIdx.x;
    if (t < NBMAX) lcnt[t] = 0;
    __syncthreads();
    int base = blockIdx.x * CHUNK;
    int end  = min(base + CHUNK, E);
    for (int i = base + t; i < end; i += 256) {
        atomicAdd(&cnt_src[src[i]], 1);
        atomicAdd(&lcnt[dst[i] >> BSHIFT], 1);
    }
    __syncthreads();
    if (t < NBMAX && lcnt[t]) atomicAdd(&bucket_cnt[t], lcnt[t]);
}

// ------- scan bucket counts (single small block) ---------------------------
__global__ __launch_bounds__(NBMAX) void bucket_scan_kernel(
    const int* __restrict__ bucket_cnt, int* __restrict__ bucket_ptr,
    int* __restrict__ bucket_cursor, int* __restrict__ row_ptr,
    int NB, int N, int E)
{
    __shared__ int sh[NBMAX];
    int t = threadIdx.x;
    sh[t] = (t < NB) ? bucket_cnt[t] : 0;
    __syncthreads();
    for (int off = 1; off < NBMAX; off <<= 1) {
        int v = (t >= off) ? sh[t - off] : 0;
        __syncthreads();
        sh[t] += v;
        __syncthreads();
    }
    int excl = (t == 0) ? 0 : sh[t - 1];
    if (t < NB) { bucket_ptr[t] = excl; bucket_cursor[t] = excl; }
    if (t == 0) { bucket_ptr[NB] = E; row_ptr[N] = E; }
}

// ------- edges pass 2: scatter packed (local_dst<<17 | src) into buckets ---
__global__ __launch_bounds__(256) void bucket_scatter_kernel(
    const int* __restrict__ src, const int* __restrict__ dst,
    int* __restrict__ bucket_cursor, int* __restrict__ packed, int E)
{
    __shared__ int lcnt[NBMAX];
    __shared__ int lbase[NBMAX];
    __shared__ int dbuf[CHUNK];      // 16 KB: dst cache, read global once
    int t = threadIdx.x;
    if (t < NBMAX) lcnt[t] = 0;
    __syncthreads();
    int base = blockIdx.x * CHUNK;
    int end  = min(base + CHUNK, E);
    for (int i = base + t; i < end; i += 256) {
        int d = dst[i];
        dbuf[i - base] = d;
        atomicAdd(&lcnt[d >> BSHIFT], 1);
    }
    __syncthreads();
    if (t < NBMAX) {
        int c = lcnt[t];
        lbase[t] = c ? atomicAdd(&bucket_cursor[t], c) : 0;
        lcnt[t] = 0;
    }
    __syncthreads();
    for (int i = base + t; i < end; i += 256) {
        int d = dbuf[i - base];
        int s = src[i];
        int b = d >> BSHIFT;
        int slot = lbase[b] + atomicAdd(&lcnt[b], 1);
        packed[slot] = ((d & (BSIZE - 1)) << SRCBITS) | s;
    }
}

// ------- per-bucket fine CSR: row_ptr, norm_dst, col -----------------------
__global__ __launch_bounds__(1024) void fine_place_kernel(
    const int* __restrict__ packed, const int* __restrict__ bucket_ptr,
    int* __restrict__ row_ptr, float* __restrict__ norm_dst,
    int* __restrict__ col, int N)
{
    __shared__ int lcnt[BSIZE];
    __shared__ int lptr[BSIZE];
    int b = blockIdx.x, t = threadIdx.x;
    int nbase = b << BSHIFT;
    int beg = bucket_ptr[b], end = bucket_ptr[b + 1];
    lcnt[t] = 0;
    __syncthreads();
    for (int i = beg + t; i < end; i += 1024)
        atomicAdd(&lcnt[packed[i] >> SRCBITS], 1);
    __syncthreads();
    for (int off = 1; off < BSIZE; off <<= 1) {
        int v = (t >= off) ? lcnt[t - off] : 0;
        __syncthreads();
        lcnt[t] += v;
        __syncthreads();
    }
    {
        int incl = lcnt[t];
        int excl = (t == 0) ? 0 : lcnt[t - 1];
        int node = nbase + t;
        if (node < N) {
            row_ptr[node] = beg + excl;
            norm_dst[node] = rsqrtf((float)max(incl - excl, 1));
        }
        lptr[t] = beg + excl;
    }
    __syncthreads();
    for (int i = beg + t; i < end; i += 1024) {
        int p = packed[i];
        int slot = atomicAdd(&lptr[p >> SRCBITS], 1);
        col[slot] = p & SRCMASK;
    }
}

// ------- norm_src from src degrees -----------------------------------------
__global__ __launch_bounds__(256) void norm_src_kernel(
    const int* __restrict__ cnt_src, float* __restrict__ norm_src, int N)
{
    int i = blockIdx.x * blockDim.x + threadIdx.x;
    if (i >= N) return;
    norm_src[i] = rsqrtf((float)max(cnt_src[i], 1));
}

// ------- fp32 -> bf16 (RNE), float4 -> ushort4 -----------------------------
__global__ __launch_bounds__(256) void convert_bf16_kernel(
    const float* __restrict__ x, u16* __restrict__ y, int total4)
{
    int i = blockIdx.x * 256 + threadIdx.x;
    if (i >= total4) return;
    float4 v = ((const float4*)x)[i];
    ushort4 o;
    o.x = f2bf(v.x); o.y = f2bf(v.y); o.z = f2bf(v.z); o.w = f2bf(v.w);
    ((ushort4*)y)[i] = o;
}

// ------- W [k][n] fp32 -> W_T [n][k] bf16 ----------------------------------
__global__ __launch_bounds__(256) void convert_wT_kernel(
    const float* __restrict__ W, u16* __restrict__ WT)
{
    int i = blockIdx.x * 256 + threadIdx.x;   // i = k*128 + n
    int k = i >> 7, n = i & 127;
    WT[n * 128 + k] = f2bf(W[i]);
}

// ---------------- gather aggregation (bf16 rows) -> bf16 agg ---------------
// one wave64 per dst node; 16 lanes/row (uint4 = 8 bf16), 4 edges in flight.
__global__ __launch_bounds__(256) void aggregate_kernel(
    const u16* __restrict__ hs, const int* __restrict__ row_ptr,
    const int* __restrict__ col, const float* __restrict__ norm_src,
    const float* __restrict__ norm_dst, u16* __restrict__ agg, int N)
{
    int n = blockIdx.x * 4 + (threadIdx.x >> 6);
    if (n >= N) return;
    int lane = threadIdx.x & 63;
    int g    = lane >> 4;     // edge-group 0..3
    int l16  = lane & 15;     // position within row (8 bf16 elems)
    int beg = row_ptr[n], end = row_ptr[n + 1];
    const uint4* h4 = (const uint4*)hs;

    float acc[8];
    #pragma unroll
    for (int j = 0; j < 8; ++j) acc[j] = 0.f;

    int i = beg + g;
    for (; i + 4 < end; i += 8) {
        int s0 = col[i], s1 = col[i + 4];
        float ns0 = norm_src[s0], ns1 = norm_src[s1];
        uint4 v0 = h4[(size_t)s0 * 16 + l16];
        uint4 v1 = h4[(size_t)s1 * 16 + l16];
        acc[0] = fmaf(bflo(v0.x), ns0, acc[0]);
        acc[1] = fmaf(bfhi(v0.x), ns0, acc[1]);
        acc[2] = fmaf(bflo(v0.y), ns0, acc[2]);
        acc[3] = fmaf(bfhi(v0.y), ns0, acc[3]);
        acc[4] = fmaf(bflo(v0.z), ns0, acc[4]);
        acc[5] = fmaf(bfhi(v0.z), ns0, acc[5]);
        acc[6] = fmaf(bflo(v0.w), ns0, acc[6]);
        acc[7] = fmaf(bfhi(v0.w), ns0, acc[7]);
        acc[0] = fmaf(bflo(v1.x), ns1, acc[0]);
        acc[1] = fmaf(bfhi(v1.x), ns1, acc[1]);
        acc[2] = fmaf(bflo(v1.y), ns1, acc[2]);
        acc[3] = fmaf(bfhi(v1.y), ns1, acc[3]);
        acc[4] = fmaf(bflo(v1.z), ns1, acc[4]);
        acc[5] = fmaf(bfhi(v1.z), ns1, acc[5]);
        acc[6] = fmaf(bflo(v1.w), ns1, acc[6]);
        acc[7] = fmaf(bfhi(v1.w), ns1, acc[7]);
    }
    if (i < end) {
        int s = col[i];
        float ns = norm_src[s];
        uint4 v = h4[(size_t)s * 16 + l16];
        acc[0] = fmaf(bflo(v.x), ns, acc[0]);
        acc[1] = fmaf(bfhi(v.x), ns, acc[1]);
        acc[2] = fmaf(bflo(v.y), ns, acc[2]);
        acc[3] = fmaf(bfhi(v.y), ns, acc[3]);
        acc[4] = fmaf(bflo(v.z), ns, acc[4]);
        acc[5] = fmaf(bfhi(v.z), ns, acc[5]);
        acc[6] = fmaf(bflo(v.w), ns, acc[6]);
        acc[7] = fmaf(bfhi(v.w), ns, acc[7]);
    }

    #pragma unroll
    for (int j = 0; j < 8; ++j) {
        acc[j] += __shfl_xor(acc[j], 16, 64);
        acc[j] += __shfl_xor(acc[j], 32, 64);
    }

    if (g == 0) {
        float nd = norm_dst[n];
        ushort4 lo, hi;
        lo.x = f2bf(acc[0] * nd); lo.y = f2bf(acc[1] * nd);
        lo.z = f2bf(acc[2] * nd); lo.w = f2bf(acc[3] * nd);
        hi.x = f2bf(acc[4] * nd); hi.y = f2bf(acc[5] * nd);
        hi.z = f2bf(acc[6] * nd); hi.w = f2bf(acc[7] * nd);
        ushort4* o = (ushort4*)(agg + (size_t)n * D + l16 * 8);
        o[0] = lo; o[1] = hi;
    }
}

// ---------------- MFMA GEMM: out = relu(A @ W + b) -------------------------
template <bool BF16_OUT>
__global__ __launch_bounds__(256) void gemm_mfma_kernel(
    const u16* __restrict__ A, const u16* __restrict__ WT,
    const float* __restrict__ bias, float* __restrict__ out_f,
    u16* __restrict__ out_b, int N)
{
    int wave = threadIdx.x >> 6;
    int lane = threadIdx.x & 63;
    int m16  = lane & 15;
    int quad = lane >> 4;
    int row_base = blockIdx.x * 128 + wave * 32;

    int rA0 = min(row_base + m16, N - 1);
    int rA1 = min(row_base + 16 + m16, N - 1);
    const short8* Arow0 = (const short8*)(A + (size_t)rA0 * D);
    const short8* Arow1 = (const short8*)(A + (size_t)rA1 * D);

    floatx4 acc0[8], acc1[8];
    #pragma unroll
    for (int c = 0; c < 8; ++c) {
        acc0[c] = (floatx4){0.f, 0.f, 0.f, 0.f};
        acc1[c] = (floatx4){0.f, 0.f, 0.f, 0.f};
    }

    #pragma unroll
    for (int q = 0; q < 4; ++q) {
        short8 a0 = Arow0[q * 4 + quad];
        short8 a1 = Arow1[q * 4 + quad];
        #pragma unroll
        for (int c = 0; c < 8; ++c) {
            short8 b = *(const short8*)(WT + (size_t)(c * 16 + m16) * D + q * 32 + quad * 8);
            acc0[c] = __builtin_amdgcn_mfma_f32_16x16x32_bf16(a0, b, acc0[c], 0, 0, 0);
            acc1[c] = __builtin_amdgcn_mfma_f32_16x16x32_bf16(a1, b, acc1[c], 0, 0, 0);
        }
    }

    #pragma unroll
    for (int c = 0; c < 8; ++c) {
        int colc = c * 16 + m16;
        float bv = bias[colc];
        #pragma unroll
        for (int r = 0; r < 4; ++r) {
            int row0 = row_base + quad * 4 + r;
            int row1 = row0 + 16;
            float v0 = fmaxf(acc0[c][r] + bv, 0.f);
            float v1 = fmaxf(acc1[c][r] + bv, 0.f);
            if (BF16_OUT) {
                if (row0 < N) out_b[(size_t)row0 * D + colc] = f2bf(v0);
                if (row1 < N) out_b[(size_t)row1 * D + colc] = f2bf(v1);
            } else {
                if (row0 < N) out_f[(size_t)row0 * D + colc] = v0;
                if (row1 < N) out_f[(size_t)row1 * D + colc] = v1;
            }
        }
    }
}

extern "C" void kernel_launch(void* const* d_in, const int* in_sizes, int n_in,
                              void* d_out, int out_size, void* d_ws, size_t ws_size,
                              hipStream_t stream)
{
    const float* features = (const float*)d_in[0];
    const int*   src      = (const int*)d_in[1];
    const int*   dst      = (const int*)d_in[2];
    const float* W1       = (const float*)d_in[3];
    const float* b1       = (const float*)d_in[4];
    const float* W2       = (const float*)d_in[5];
    const float* b2       = (const float*)d_in[6];
    float*       out      = (float*)d_out;

    const int N = in_sizes[0] / D;
    const int E = in_sizes[1];
    const int NB = (N + BSIZE - 1) >> BSHIFT;

    // workspace layout
    u16*   agg_bf   = (u16*)d_ws;                   // N*D bf16 (packed overlaid)
    int*   packed   = (int*)agg_bf;                 // E ints (6.4MB <= 25.6MB)
    u16*   feat_bf  = agg_bf + (size_t)N * D;       // N*D bf16
    u16*   hs_bf    = feat_bf + (size_t)N * D;      // N*D bf16
    u16*   wT1      = hs_bf + (size_t)N * D;        // 16384 bf16
    u16*   wT2      = wT1 + D * D;                  // 16384 bf16
    float* norm_src = (float*)(wT2 + D * D);        // N
    float* norm_dst = norm_src + N;                 // N
    int*   iws          = (int*)(norm_dst + N);
    int*   cnt_src      = iws;                      // N
    int*   bucket_cnt   = cnt_src + N;              // NBMAX (memset with cnt_src)
    int*   row_ptr      = bucket_cnt + NBMAX;       // N+1
    int*   col          = row_ptr + N + 1;          // E
    int*   bucket_ptr   = col + E;                  // NBMAX+1
    int*   bucket_cursor= bucket_ptr + NBMAX + 1;   // NBMAX

    const int nb  = (N + 255) / 256;
    const int ebk = (E + CHUNK - 1) / CHUNK;
    const int gemm_blocks = (N + 127) / 128;
    const int agg_blocks  = (N + 3) / 4;
    const int cv_blocks   = (N * 32 + 255) / 256;
    const int wt_blocks   = (D * D + 255) / 256;

    // ---- CSR build (bucketed, packed, write-coalesced) + conversions ----
    hipMemsetAsync(cnt_src, 0, ((size_t)N + NBMAX) * sizeof(int), stream);
    hist_bucket_kernel<<<ebk, 256, 0, stream>>>(src, dst, cnt_src, bucket_cnt, E);
    bucket_scan_kernel<<<1, NBMAX, 0, stream>>>(bucket_cnt, bucket_ptr, bucket_cursor, row_ptr, NB, N, E);
    bucket_scatter_kernel<<<ebk, 256, 0, stream>>>(src, dst, bucket_cursor, packed, E);
    norm_src_kernel<<<nb, 256, 0, stream>>>(cnt_src, norm_src, N);
    fine_place_kernel<<<NB, 1024, 0, stream>>>(packed, bucket_ptr, row_ptr, norm_dst, col, N);
    convert_bf16_kernel<<<cv_blocks, 256, 0, stream>>>(features, feat_bf, N * 32);
    convert_wT_kernel<<<wt_blocks, 256, 0, stream>>>(W1, wT1);
    convert_wT_kernel<<<wt_blocks, 256, 0, stream>>>(W2, wT2);

    // ---- layer 1 ----
    aggregate_kernel<<<agg_blocks, 256, 0, stream>>>(feat_bf, row_ptr, col, norm_src, norm_dst, agg_bf, N);
    gemm_mfma_kernel<true><<<gemm_blocks, 256, 0, stream>>>(agg_bf, wT1, b1, nullptr, hs_bf, N);

    // ---- layer 2 ----
    aggregate_kernel<<<agg_blocks, 256, 0, stream>>>(hs_bf, row_ptr, col, norm_src, norm_dst, agg_bf, N);
    gemm_mfma_kernel<false><<<gemm_blocks, 256, 0, stream>>>(agg_bf, wT2, b2, out, nullptr, N);
}